// Round 7
// baseline (3137.660 us; speedup 1.0000x reference)
//
#include <hip/hip_runtime.h>
#include <math.h>

// ---------------- problem constants ----------------
constexpr int BB   = 4;
constexpr int TT   = 400;
constexpr int FF   = 1025;
constexpr int NFFT = 2048;
constexpr int HOP  = 512;
constexpr int PADD = 1024;
constexpr int LL   = HOP * (TT - 1);        // 204288
constexpr int LPAD = NFFT + HOP * (TT - 1); // 206336
constexpr int NITER = 60;
constexpr double MOM = 0.99 / 1.99;
constexpr double EPSV = 1e-16;
constexpr double DPI = 3.14159265358979323846;

// workspace offsets in DOUBLES (all even -> 16B alignment)
constexpr size_t OFF_TW1024 = 0;          // 1024 double2 = 2048 d
constexpr size_t OFF_TW2048 = 2048;       // 1025 double2 = 2050 d
constexpr size_t OFF_TPR    = 4098;       // B*T*F double2 = 3280000 d
constexpr size_t OFF_FRM0   = 3284098;    // B*T*2048 = 3276800 d
constexpr size_t OFF_FRM1   = 6560898;    // 3276800 d
constexpr size_t OFF_WIN32  = 9837698;    // f32 window: 2048 f = 1024 d
constexpr size_t OFF_WSQ32  = 9838722;    // f32 wsq divisor: 206336 f = 103168 d
constexpr size_t WS_DOUBLES = 9941890;    // ~79.5 MB

__device__ __forceinline__ double2 cmuld(double2 a, double2 b) {
    return make_double2(a.x * b.x - a.y * b.y, a.x * b.y + a.y * b.x);
}

// ---------------- numpy SIMD float32 cosine, bit-exact replica ----------------
__device__ __forceinline__ float np_cosf(float x) {
    const float rint_cvt = 0x1.800000p+23f;  // 12582912.0f
    float qf = __builtin_fmaf(x, 0x1.45f306p-1f, rint_cvt) - rint_cvt;
    float r = __builtin_fmaf(qf, -0x1.921fb0p+0f, x);
    r = __builtin_fmaf(qf, -0x1.5110b4p-22f, r);
    r = __builtin_fmaf(qf, -0x1.846988p-48f, r);
    r = __builtin_fmaf(qf, -0x1.8cc966p-73f, r);
    int q = (int)qf + 1;  // cos(x) = sin(x + pi/2)
    float r2 = r * r;
    float cosp = __builtin_fmaf(0x1.98e616p-16f, r2, -0x1.6c06dcp-10f);
    cosp = __builtin_fmaf(cosp, r2, 0x1.55553cp-5f);
    cosp = __builtin_fmaf(cosp, r2, -0x1.000000p-1f);
    cosp = __builtin_fmaf(cosp, r2, 0x1.000000p+0f);
    float sinp = __builtin_fmaf(0x1.7d3bbcp-19f, r2, -0x1.a06bbap-13f);
    sinp = __builtin_fmaf(sinp, r2, 0x1.11119ap-7f);
    sinp = __builtin_fmaf(sinp, r2, -0x1.555548p-3f);
    sinp = sinp * r2;
    sinp = __builtin_fmaf(sinp, r, r);
    float res = (q & 1) ? cosp : sinp;
    return (q & 2) ? -res : res;
}

// ---------------- init kernels ----------------
__global__ void k_init_tables(double2* tw1024, double2* tw2048, float* win) {
    int n = blockIdx.x * blockDim.x + threadIdx.x;
    if (n < 1024) {
        double th = -2.0 * DPI * (double)n / 1024.0;
        double s, c; sincos(th, &s, &c);
        tw1024[n] = make_double2(c, s);
    }
    if (n < 1025) {
        double th = -2.0 * DPI * (double)n / 2048.0;
        double s, c; sincos(th, &s, &c);
        tw2048[n] = make_double2(c, s);
    }
    if (n < 2048) {
        const float TWO_PI_F = 6.283185307179586f;
        float ang = __fdiv_rn(__fmul_rn(TWO_PI_F, (float)n), 2048.0f);
        float c = np_cosf(ang);
        win[n] = __fsub_rn(0.5f, __fmul_rn(0.5f, c));
    }
}

__global__ void k_init_wsq(const float* __restrict__ win, float* __restrict__ wsq) {
    int m = blockIdx.x * blockDim.x + threadIdx.x;
    if (m >= LPAD) return;
    int tlo = (m - (NFFT - HOP)) >> 9;
    if (tlo < 0) tlo = 0;
    int thi = m >> 9;
    if (thi > TT - 1) thi = TT - 1;
    float s = 0.0f;
    for (int t = tlo; t <= thi; ++t) {
        float w = win[m - (t << 9)];
        s = __fadd_rn(s, __fmul_rn(w, w));
    }
    wsq[m] = (s > 1e-11f) ? s : 1.0f;
}

__global__ void k_init_state(double2* __restrict__ tpr) {
    int i = blockIdx.x * blockDim.x + threadIdx.x;
    if (i < BB * TT * FF) tpr[i] = make_double2(0.0, 0.0);
}

// ---------------- 1024-pt radix-4 Stockham FFT in LDS (fp64) ----------------
// DIR=-1 forward (e^{-i}), DIR=+1 inverse (unnormalized). 256 threads.
// Caller must __syncthreads() after filling bufA. Result lands in bufB.
template <int DIR>
__device__ void fft1024(double2* bufA, double2* bufB, const double2* __restrict__ tw, int tid) {
    double2* src = bufA;
    double2* dst = bufB;
#pragma unroll
    for (int s = 0; s < 5; ++s) {
        const int p = 1 << (2 * s);
        int k = tid & (p - 1);
        int j = ((tid - k) << 2) + k;
        double2 a = src[tid];
        double2 b = src[tid + 256];
        double2 c = src[tid + 512];
        double2 d = src[tid + 768];
        int t1 = k << (8 - 2 * s);
        double2 w1 = tw[t1 & 1023];
        double2 w2 = tw[(2 * t1) & 1023];
        double2 w3 = tw[(3 * t1) & 1023];
        if (DIR > 0) { w1.y = -w1.y; w2.y = -w2.y; w3.y = -w3.y; }
        b = cmuld(b, w1);
        c = cmuld(c, w2);
        d = cmuld(d, w3);
        double2 u0 = make_double2(a.x + c.x, a.y + c.y);
        double2 u1 = make_double2(a.x - c.x, a.y - c.y);
        double2 v0 = make_double2(b.x + d.x, b.y + d.y);
        double2 v1 = make_double2(b.x - d.x, b.y - d.y);
        double2 o0 = make_double2(u0.x + v0.x, u0.y + v0.y);
        double2 o2 = make_double2(u0.x - v0.x, u0.y - v0.y);
        double2 o1, o3;
        if (DIR < 0) {
            o1 = make_double2(u1.x + v1.y, u1.y - v1.x);
            o3 = make_double2(u1.x - v1.y, u1.y + v1.x);
        } else {
            o1 = make_double2(u1.x - v1.y, u1.y + v1.x);
            o3 = make_double2(u1.x + v1.y, u1.y - v1.x);
        }
        dst[j] = o0;
        dst[j + p] = o1;
        dst[j + 2 * p] = o2;
        dst[j + 3 * p] = o3;
        __syncthreads();
        double2* tmp = src; src = dst; dst = tmp;
    }
}

// ---------------- initial frames: istft of (mag, 0) ----------------
__global__ __launch_bounds__(256) void k_istft_first(
    const float* __restrict__ mag,
    const double2* __restrict__ tw1024, const double2* __restrict__ tw2048,
    const float* __restrict__ win, double* __restrict__ frames_out) {
    __shared__ double2 X[1025];
    __shared__ double2 ZB[1024];
    const int fid = blockIdx.x;
    const int tid = threadIdx.x;
    const float* mg = mag + (size_t)fid * FF;
#pragma unroll
    for (int q = 0; q < 4; ++q) {
        int k = tid + 256 * q;
        X[k] = make_double2((double)mg[k], 0.0);
    }
    if (tid == 0) X[1024] = make_double2((double)mg[1024], 0.0);
    __syncthreads();
#pragma unroll
    for (int q = 0; q < 4; ++q) {
        int k = tid + 256 * q;
        double2 Xk = X[k];
        double2 Xc = X[1024 - k];
        if (k == 0) { Xk.y = 0.0; Xc.y = 0.0; }
        Xc.y = -Xc.y;
        double2 A = make_double2(0.5 * (Xk.x + Xc.x), 0.5 * (Xk.y + Xc.y));
        double2 D = make_double2(0.5 * (Xk.x - Xc.x), 0.5 * (Xk.y - Xc.y));
        double2 w = tw2048[k];
        w.y = -w.y;
        double2 Bv = cmuld(w, D);
        ZB[k] = make_double2(A.x - Bv.y, A.y + Bv.x);
    }
    __syncthreads();
    fft1024<1>(ZB, X, tw1024, tid);
    double2* fr = reinterpret_cast<double2*>(frames_out + (size_t)fid * NFFT);
    const float2* w2 = reinterpret_cast<const float2*>(win);
#pragma unroll
    for (int q = 0; q < 4; ++q) {
        int m = tid + 256 * q;
        double2 z = X[m];
        float2 wv = w2[m];
        fr[m] = make_double2(z.x * (1.0 / 1024.0) * (double)wv.x,
                             z.y * (1.0 / 1024.0) * (double)wv.y);
    }
}

// ---------------- fused per-iteration kernel ----------------
// OLA(frames_in) -> windowed segment -> fwd FFT -> untwist -> momentum/phase
// update (tpr in global) -> mag*ang -> pre-twist -> inv FFT -> window ->
// frames_out. All arithmetic bit-identical to the split version.
__global__ __launch_bounds__(256) void k_mono(
    const double* __restrict__ frames_in, double* __restrict__ frames_out,
    const float* __restrict__ mag, double2* __restrict__ tpr,
    const double2* __restrict__ tw1024, const double2* __restrict__ tw2048,
    const float* __restrict__ win, const float* __restrict__ wsq) {
    __shared__ double2 X[1025];
    __shared__ double2 ZB[1024];
    const int fid = blockIdx.x;
    const int b = fid / TT;
    const int t = fid - b * TT;
    const int tid = threadIdx.x;
    const double* fb = frames_in + (size_t)b * TT * NFFT;
    const float2* w2 = reinterpret_cast<const float2*>(win);
    const int t512 = t * HOP;
    // stage 1: OLA + reflect + wsq-normalize + window -> X
#pragma unroll
    for (int q = 0; q < 4; ++q) {
        int k = tid + 256 * q;
        double xv0, xv1;
#pragma unroll
        for (int h = 0; h < 2; ++h) {
            int p = t512 + 2 * k + h;
            int j = p - PADD;
            if (j < 0) j = -j;
            else if (j >= LL) j = 2 * LL - 2 - j;
            int m = j + PADD;
            int tlo = (m - (NFFT - HOP)) >> 9;
            if (tlo < 0) tlo = 0;
            int thi = m >> 9;
            if (thi > TT - 1) thi = TT - 1;
            double s = 0.0;
            for (int u = tlo; u <= thi; ++u) s += fb[(size_t)u * NFFT + (m - (u << 9))];
            double val = s / (double)wsq[m];
            if (h == 0) xv0 = val; else xv1 = val;
        }
        float2 wv = w2[k];
        X[k] = make_double2(xv0 * (double)wv.x, xv1 * (double)wv.y);
    }
    __syncthreads();
    fft1024<-1>(X, ZB, tw1024, tid);  // forward; result in ZB
    // stage 3: untwist + momentum/phase update + new spectrum -> X
    size_t base = (size_t)fid * FF;
    const float* mg = mag + base;
#pragma unroll
    for (int q = 0; q < 5; ++q) {
        int k = tid + 256 * q;
        if (k <= 1024) {
            double2 Zk = ZB[k & 1023];
            double2 Zc = ZB[(1024 - k) & 1023];
            Zc.y = -Zc.y;
            double2 A = make_double2(0.5 * (Zk.x + Zc.x), 0.5 * (Zk.y + Zc.y));
            double2 D = make_double2(Zk.x - Zc.x, Zk.y - Zc.y);
            double2 Bv = make_double2(0.5 * D.y, -0.5 * D.x);  // -i*D/2
            double2 w = tw2048[k];
            double2 wB = cmuld(w, Bv);
            double2 Xk = make_double2(A.x + wB.x, A.y + wB.y);
            double2 tp = tpr[base + k];
            double2 a = make_double2(Xk.x - MOM * tp.x, Xk.y - MOM * tp.y);
            double r = sqrt(a.x * a.x + a.y * a.y);
            double d = r + EPSV;
            tpr[base + k] = Xk;
            double m = (double)mg[k];
            X[k] = make_double2(m * (a.x / d), m * (a.y / d));
        }
    }
    __syncthreads();
    // stage 4: pre-twist -> ZB
#pragma unroll
    for (int q = 0; q < 4; ++q) {
        int k = tid + 256 * q;
        double2 Xk = X[k];
        double2 Xc = X[1024 - k];
        if (k == 0) { Xk.y = 0.0; Xc.y = 0.0; }
        Xc.y = -Xc.y;
        double2 A = make_double2(0.5 * (Xk.x + Xc.x), 0.5 * (Xk.y + Xc.y));
        double2 D = make_double2(0.5 * (Xk.x - Xc.x), 0.5 * (Xk.y - Xc.y));
        double2 w = tw2048[k];
        w.y = -w.y;
        double2 Bv = cmuld(w, D);
        ZB[k] = make_double2(A.x - Bv.y, A.y + Bv.x);
    }
    __syncthreads();
    fft1024<1>(ZB, X, tw1024, tid);  // inverse; result in X
    double2* fr = reinterpret_cast<double2*>(frames_out + (size_t)fid * NFFT);
#pragma unroll
    for (int q = 0; q < 4; ++q) {
        int m = tid + 256 * q;
        double2 z = X[m];
        float2 wv = w2[m];
        fr[m] = make_double2(z.x * (1.0 / 1024.0) * (double)wv.x,
                             z.y * (1.0 / 1024.0) * (double)wv.y);
    }
}

// ---------------- final: overlap-add -> trimmed fp32 output ----------------
__global__ __launch_bounds__(256) void k_ola_out(
    const double* __restrict__ frames, const float* __restrict__ wsq,
    float* __restrict__ out) {
    int gid = blockIdx.x * 256 + threadIdx.x;  // exactly B*L threads
    int b = gid / LL;
    int j = gid - b * LL;
    int m = j + PADD;
    int tlo = (m - (NFFT - HOP)) >> 9;
    if (tlo < 0) tlo = 0;
    int thi = m >> 9;
    if (thi > TT - 1) thi = TT - 1;
    const double* fb = frames + (size_t)b * TT * NFFT;
    double s = 0.0;
    for (int t = tlo; t <= thi; ++t) s += fb[(size_t)t * NFFT + (m - (t << 9))];
    out[gid] = (float)(s / (double)wsq[m]);
}

extern "C" void kernel_launch(void* const* d_in, const int* in_sizes, int n_in,
                              void* d_out, int out_size, void* d_ws, size_t ws_size,
                              hipStream_t stream) {
    if (ws_size < WS_DOUBLES * sizeof(double)) return;  // fail loudly if ws too small
    const float* mag = (const float*)d_in[0];  // (B,T,F) fp32
    double* ws = (double*)d_ws;
    double2* tw1024 = (double2*)(ws + OFF_TW1024);
    double2* tw2048 = (double2*)(ws + OFF_TW2048);
    double2* tprv   = (double2*)(ws + OFF_TPR);
    double* frm0    = ws + OFF_FRM0;
    double* frm1    = ws + OFF_FRM1;
    float* win      = (float*)(ws + OFF_WIN32);
    float* wsq      = (float*)(ws + OFF_WSQ32);

    k_init_tables<<<8, 256, 0, stream>>>(tw1024, tw2048, win);
    k_init_wsq<<<LPAD / 256, 256, 0, stream>>>(win, wsq);
    k_init_state<<<(BB * TT * FF + 255) / 256, 256, 0, stream>>>(tprv);

    k_istft_first<<<BB * TT, 256, 0, stream>>>(mag, tw1024, tw2048, win, frm0);
    for (int it = 0; it < NITER; ++it) {
        double* fin  = (it & 1) ? frm1 : frm0;
        double* fout = (it & 1) ? frm0 : frm1;
        k_mono<<<BB * TT, 256, 0, stream>>>(fin, fout, mag, tprv,
                                            tw1024, tw2048, win, wsq);
    }
    // after 60 iterations the final frames are in frm0
    k_ola_out<<<(BB * LL) / 256, 256, 0, stream>>>(frm0, wsq, (float*)d_out);
}

// Round 8
// 2350.378 us; speedup vs baseline: 1.3350x; 1.3350x over previous
//
#include <hip/hip_runtime.h>
#include <math.h>

// ---------------- problem constants ----------------
constexpr int BB   = 4;
constexpr int TT   = 400;
constexpr int FF   = 1025;
constexpr int NFFT = 2048;
constexpr int HOP  = 512;
constexpr int PADD = 1024;
constexpr int LL   = HOP * (TT - 1);        // 204288
constexpr int LPAD = NFFT + HOP * (TT - 1); // 206336
constexpr int NITER = 60;
constexpr double MOM = 0.99 / 1.99;
constexpr double EPSV = 1e-16;
constexpr double DPI = 3.14159265358979323846;

// workspace offsets in DOUBLES (all even -> 16B alignment)
constexpr size_t OFF_TW1024 = 0;          // 1024 double2 = 2048 d
constexpr size_t OFF_TW2048 = 2048;       // 1025 double2 = 2050 d
constexpr size_t OFF_TPR    = 4098;       // B*T*F double2 = 3280000 d
constexpr size_t OFF_FRM    = 3284098;    // B*T*2048 = 3276800 d
constexpr size_t OFF_XP     = 6560898;    // B*LPAD = 825344 d
constexpr size_t OFF_WIN32  = 7386242;    // f32 window: 2048 f = 1024 d
constexpr size_t OFF_WSQ32  = 7387266;    // f32 wsq divisor: 206336 f = 103168 d
constexpr size_t WS_DOUBLES = 7490434;    // ~59.9 MB

__device__ __forceinline__ double2 cmuld(double2 a, double2 b) {
    return make_double2(a.x * b.x - a.y * b.y, a.x * b.y + a.y * b.x);
}

// ---------------- numpy SIMD float32 cosine, bit-exact replica ----------------
__device__ __forceinline__ float np_cosf(float x) {
    const float rint_cvt = 0x1.800000p+23f;  // 12582912.0f
    float qf = __builtin_fmaf(x, 0x1.45f306p-1f, rint_cvt) - rint_cvt;
    float r = __builtin_fmaf(qf, -0x1.921fb0p+0f, x);
    r = __builtin_fmaf(qf, -0x1.5110b4p-22f, r);
    r = __builtin_fmaf(qf, -0x1.846988p-48f, r);
    r = __builtin_fmaf(qf, -0x1.8cc966p-73f, r);
    int q = (int)qf + 1;  // cos(x) = sin(x + pi/2)
    float r2 = r * r;
    float cosp = __builtin_fmaf(0x1.98e616p-16f, r2, -0x1.6c06dcp-10f);
    cosp = __builtin_fmaf(cosp, r2, 0x1.55553cp-5f);
    cosp = __builtin_fmaf(cosp, r2, -0x1.000000p-1f);
    cosp = __builtin_fmaf(cosp, r2, 0x1.000000p+0f);
    float sinp = __builtin_fmaf(0x1.7d3bbcp-19f, r2, -0x1.a06bbap-13f);
    sinp = __builtin_fmaf(sinp, r2, 0x1.11119ap-7f);
    sinp = __builtin_fmaf(sinp, r2, -0x1.555548p-3f);
    sinp = sinp * r2;
    sinp = __builtin_fmaf(sinp, r, r);
    float res = (q & 1) ? cosp : sinp;
    return (q & 2) ? -res : res;
}

// ---------------- init kernels ----------------
__global__ void k_init_tables(double2* tw1024, double2* tw2048, float* win) {
    int n = blockIdx.x * blockDim.x + threadIdx.x;
    if (n < 1024) {
        double th = -2.0 * DPI * (double)n / 1024.0;
        double s, c; sincos(th, &s, &c);
        tw1024[n] = make_double2(c, s);
    }
    if (n < 1025) {
        double th = -2.0 * DPI * (double)n / 2048.0;
        double s, c; sincos(th, &s, &c);
        tw2048[n] = make_double2(c, s);
    }
    if (n < 2048) {
        const float TWO_PI_F = 6.283185307179586f;
        float ang = __fdiv_rn(__fmul_rn(TWO_PI_F, (float)n), 2048.0f);
        float c = np_cosf(ang);
        win[n] = __fsub_rn(0.5f, __fmul_rn(0.5f, c));
    }
}

__global__ void k_init_wsq(const float* __restrict__ win, float* __restrict__ wsq) {
    int m = blockIdx.x * blockDim.x + threadIdx.x;
    if (m >= LPAD) return;
    int tlo = (m - (NFFT - HOP)) >> 9;
    if (tlo < 0) tlo = 0;
    int thi = m >> 9;
    if (thi > TT - 1) thi = TT - 1;
    float s = 0.0f;
    for (int t = tlo; t <= thi; ++t) {
        float w = win[m - (t << 9)];
        s = __fadd_rn(s, __fmul_rn(w, w));
    }
    wsq[m] = (s > 1e-11f) ? s : 1.0f;
}

__global__ void k_init_state(double2* __restrict__ tpr) {
    int i = blockIdx.x * blockDim.x + threadIdx.x;
    if (i < BB * TT * FF) tpr[i] = make_double2(0.0, 0.0);
}

// ---------------- 1024-pt radix-4 Stockham FFT, in-place single LDS buffer ----------------
// DIR=-1 forward (e^{-i}), DIR=+1 inverse (unnormalized). 256 threads.
// Identical arithmetic to the 2-buffer version; read-sync-write-sync per stage.
// Caller must __syncthreads() after filling buf.
template <int DIR>
__device__ void fft1024_ip(double2* buf, const double2* __restrict__ tw, int tid) {
#pragma unroll
    for (int s = 0; s < 5; ++s) {
        const int p = 1 << (2 * s);
        int k = tid & (p - 1);
        int j = ((tid - k) << 2) + k;
        double2 a = buf[tid];
        double2 b = buf[tid + 256];
        double2 c = buf[tid + 512];
        double2 d = buf[tid + 768];
        int t1 = k << (8 - 2 * s);
        double2 w1 = tw[t1 & 1023];
        double2 w2 = tw[(2 * t1) & 1023];
        double2 w3 = tw[(3 * t1) & 1023];
        if (DIR > 0) { w1.y = -w1.y; w2.y = -w2.y; w3.y = -w3.y; }
        b = cmuld(b, w1);
        c = cmuld(c, w2);
        d = cmuld(d, w3);
        double2 u0 = make_double2(a.x + c.x, a.y + c.y);
        double2 u1 = make_double2(a.x - c.x, a.y - c.y);
        double2 v0 = make_double2(b.x + d.x, b.y + d.y);
        double2 v1 = make_double2(b.x - d.x, b.y - d.y);
        double2 o0 = make_double2(u0.x + v0.x, u0.y + v0.y);
        double2 o2 = make_double2(u0.x - v0.x, u0.y - v0.y);
        double2 o1, o3;
        if (DIR < 0) {
            o1 = make_double2(u1.x + v1.y, u1.y - v1.x);
            o3 = make_double2(u1.x - v1.y, u1.y + v1.x);
        } else {
            o1 = make_double2(u1.x - v1.y, u1.y + v1.x);
            o3 = make_double2(u1.x + v1.y, u1.y - v1.x);
        }
        __syncthreads();  // all reads done
        buf[j] = o0;
        buf[j + p] = o1;
        buf[j + 2 * p] = o2;
        buf[j + 3 * p] = o3;
        __syncthreads();  // all writes done
    }
}

// ---------------- initial frames: istft of (mag, 0) ----------------
__global__ __launch_bounds__(256) void k_istft_first(
    const float* __restrict__ mag,
    const double2* __restrict__ tw1024, const double2* __restrict__ tw2048,
    const float* __restrict__ win, double* __restrict__ frames_out) {
    __shared__ double2 X[1025];
    const int fid = blockIdx.x;
    const int tid = threadIdx.x;
    const float* mg = mag + (size_t)fid * FF;
#pragma unroll
    for (int q = 0; q < 4; ++q) {
        int k = tid + 256 * q;
        X[k] = make_double2((double)mg[k], 0.0);
    }
    if (tid == 0) X[1024] = make_double2((double)mg[1024], 0.0);
    __syncthreads();
    // pre-twist (read to regs, sync, write in place)
    double2 Pk[4], Pc[4];
#pragma unroll
    for (int q = 0; q < 4; ++q) {
        int k = tid + 256 * q;
        Pk[q] = X[k];
        Pc[q] = X[1024 - k];
    }
    __syncthreads();
#pragma unroll
    for (int q = 0; q < 4; ++q) {
        int k = tid + 256 * q;
        double2 Xk = Pk[q];
        double2 Xc = Pc[q];
        if (k == 0) { Xk.y = 0.0; Xc.y = 0.0; }
        Xc.y = -Xc.y;
        double2 A = make_double2(0.5 * (Xk.x + Xc.x), 0.5 * (Xk.y + Xc.y));
        double2 D = make_double2(0.5 * (Xk.x - Xc.x), 0.5 * (Xk.y - Xc.y));
        double2 w = tw2048[k];
        w.y = -w.y;
        double2 Bv = cmuld(w, D);
        X[k] = make_double2(A.x - Bv.y, A.y + Bv.x);
    }
    __syncthreads();
    fft1024_ip<1>(X, tw1024, tid);
    double2* fr = reinterpret_cast<double2*>(frames_out + (size_t)fid * NFFT);
    const float2* w2 = reinterpret_cast<const float2*>(win);
#pragma unroll
    for (int q = 0; q < 4; ++q) {
        int m = tid + 256 * q;
        double2 z = X[m];
        float2 wv = w2[m];
        fr[m] = make_double2(z.x * (1.0 / 1024.0) * (double)wv.x,
                             z.y * (1.0 / 1024.0) * (double)wv.y);
    }
}

// ---------------- OLA: frames -> normalized reflect-padded signal xp ----------------
__global__ __launch_bounds__(256) void k_ola(
    const double* __restrict__ frames, const float* __restrict__ wsq,
    double* __restrict__ xp) {
    int gid = blockIdx.x * 256 + threadIdx.x;  // exactly B*LPAD threads
    int b = gid / LPAD;
    int p = gid - b * LPAD;
    int j = p - PADD;
    if (j < 0) j = -j;
    else if (j >= LL) j = 2 * LL - 2 - j;
    int m = j + PADD;
    int tlo = (m - (NFFT - HOP)) >> 9;
    if (tlo < 0) tlo = 0;
    int thi = m >> 9;
    if (thi > TT - 1) thi = TT - 1;
    const double* fb = frames + (size_t)b * TT * NFFT;
    double s = 0.0;
    for (int t = tlo; t <= thi; ++t) s += fb[(size_t)t * NFFT + (m - (t << 9))];
    xp[gid] = s / (double)wsq[m];
}

// ---------------- fused: stft + phase update + istft -> frames ----------------
__global__ __launch_bounds__(256) void k_fused(
    const double* __restrict__ xp, double* __restrict__ frames_out,
    const float* __restrict__ mag, double2* __restrict__ tpr,
    const double2* __restrict__ tw1024, const double2* __restrict__ tw2048,
    const float* __restrict__ win) {
    __shared__ double2 X[1025];
    const int fid = blockIdx.x;
    const int b = fid / TT;
    const int t = fid - b * TT;
    const int tid = threadIdx.x;
    const double2* xb = reinterpret_cast<const double2*>(xp + (size_t)b * LPAD + (size_t)t * HOP);
    const float2* w2 = reinterpret_cast<const float2*>(win);
    // stage 1: load windowed segment (packed as 1024 complex)
#pragma unroll
    for (int q = 0; q < 4; ++q) {
        int k = tid + 256 * q;
        double2 v = xb[k];
        float2 wv = w2[k];
        X[k] = make_double2(v.x * (double)wv.x, v.y * (double)wv.y);
    }
    __syncthreads();
    fft1024_ip<-1>(X, tw1024, tid);  // forward; result in X[0..1023]
    // stage 2: untwist + momentum/phase update + new spectrum (in place)
    size_t base = (size_t)fid * FF;
    const float* mg = mag + base;
    double2 Zk[4], Zc[4];
#pragma unroll
    for (int q = 0; q < 4; ++q) {
        int k = tid + 256 * q;            // 0..1023
        Zk[q] = X[k];
        Zc[q] = X[(1024 - k) & 1023];
    }
    __syncthreads();  // all reads done; X now writable
#pragma unroll
    for (int q = 0; q < 4; ++q) {
        int k = tid + 256 * q;
        double2 zk = Zk[q];
        double2 zc = Zc[q];
        zc.y = -zc.y;
        double2 A = make_double2(0.5 * (zk.x + zc.x), 0.5 * (zk.y + zc.y));
        double2 D = make_double2(zk.x - zc.x, zk.y - zc.y);
        double2 Bv = make_double2(0.5 * D.y, -0.5 * D.x);  // -i*D/2
        double2 w = tw2048[k];
        double2 wB = cmuld(w, Bv);
        double2 Xk = make_double2(A.x + wB.x, A.y + wB.y);
        double2 tp = tpr[base + k];
        double2 a = make_double2(Xk.x - MOM * tp.x, Xk.y - MOM * tp.y);
        double r = sqrt(a.x * a.x + a.y * a.y);
        double d = r + EPSV;
        tpr[base + k] = Xk;
        double m = (double)mg[k];
        X[k] = make_double2(m * (a.x / d), m * (a.y / d));
    }
    if (tid == 0) {
        // k = 1024: Zk = Zc = X-old[0], held in Zk[0]/Zc[0] of this thread
        const int k = 1024;
        double2 zk = Zk[0];
        double2 zc = Zc[0];
        zc.y = -zc.y;
        double2 A = make_double2(0.5 * (zk.x + zc.x), 0.5 * (zk.y + zc.y));
        double2 D = make_double2(zk.x - zc.x, zk.y - zc.y);
        double2 Bv = make_double2(0.5 * D.y, -0.5 * D.x);
        double2 w = tw2048[k];
        double2 wB = cmuld(w, Bv);
        double2 Xk = make_double2(A.x + wB.x, A.y + wB.y);
        double2 tp = tpr[base + k];
        double2 a = make_double2(Xk.x - MOM * tp.x, Xk.y - MOM * tp.y);
        double r = sqrt(a.x * a.x + a.y * a.y);
        double d = r + EPSV;
        tpr[base + k] = Xk;
        double m = (double)mg[k];
        X[k] = make_double2(m * (a.x / d), m * (a.y / d));
    }
    __syncthreads();
    // stage 3: pre-twist (read to regs, sync, write in place)
    double2 Pk[4], Pc[4];
#pragma unroll
    for (int q = 0; q < 4; ++q) {
        int k = tid + 256 * q;
        Pk[q] = X[k];
        Pc[q] = X[1024 - k];
    }
    __syncthreads();
#pragma unroll
    for (int q = 0; q < 4; ++q) {
        int k = tid + 256 * q;
        double2 Xk = Pk[q];
        double2 Xc = Pc[q];
        if (k == 0) { Xk.y = 0.0; Xc.y = 0.0; }
        Xc.y = -Xc.y;
        double2 A = make_double2(0.5 * (Xk.x + Xc.x), 0.5 * (Xk.y + Xc.y));
        double2 D = make_double2(0.5 * (Xk.x - Xc.x), 0.5 * (Xk.y - Xc.y));
        double2 w = tw2048[k];
        w.y = -w.y;
        double2 Bv = cmuld(w, D);
        X[k] = make_double2(A.x - Bv.y, A.y + Bv.x);
    }
    __syncthreads();
    fft1024_ip<1>(X, tw1024, tid);  // inverse; result in X
    double2* fr = reinterpret_cast<double2*>(frames_out + (size_t)fid * NFFT);
#pragma unroll
    for (int q = 0; q < 4; ++q) {
        int m = tid + 256 * q;
        double2 z = X[m];
        float2 wv = w2[m];
        fr[m] = make_double2(z.x * (1.0 / 1024.0) * (double)wv.x,
                             z.y * (1.0 / 1024.0) * (double)wv.y);
    }
}

// ---------------- final: overlap-add -> trimmed fp32 output ----------------
__global__ __launch_bounds__(256) void k_ola_out(
    const double* __restrict__ frames, const float* __restrict__ wsq,
    float* __restrict__ out) {
    int gid = blockIdx.x * 256 + threadIdx.x;  // exactly B*L threads
    int b = gid / LL;
    int j = gid - b * LL;
    int m = j + PADD;
    int tlo = (m - (NFFT - HOP)) >> 9;
    if (tlo < 0) tlo = 0;
    int thi = m >> 9;
    if (thi > TT - 1) thi = TT - 1;
    const double* fb = frames + (size_t)b * TT * NFFT;
    double s = 0.0;
    for (int t = tlo; t <= thi; ++t) s += fb[(size_t)t * NFFT + (m - (t << 9))];
    out[gid] = (float)(s / (double)wsq[m]);
}

extern "C" void kernel_launch(void* const* d_in, const int* in_sizes, int n_in,
                              void* d_out, int out_size, void* d_ws, size_t ws_size,
                              hipStream_t stream) {
    if (ws_size < WS_DOUBLES * sizeof(double)) return;  // fail loudly if ws too small
    const float* mag = (const float*)d_in[0];  // (B,T,F) fp32
    double* ws = (double*)d_ws;
    double2* tw1024 = (double2*)(ws + OFF_TW1024);
    double2* tw2048 = (double2*)(ws + OFF_TW2048);
    double2* tprv   = (double2*)(ws + OFF_TPR);
    double* frames  = ws + OFF_FRM;
    double* xp      = ws + OFF_XP;
    float* win      = (float*)(ws + OFF_WIN32);
    float* wsq      = (float*)(ws + OFF_WSQ32);

    k_init_tables<<<8, 256, 0, stream>>>(tw1024, tw2048, win);
    k_init_wsq<<<LPAD / 256, 256, 0, stream>>>(win, wsq);
    k_init_state<<<(BB * TT * FF + 255) / 256, 256, 0, stream>>>(tprv);

    k_istft_first<<<BB * TT, 256, 0, stream>>>(mag, tw1024, tw2048, win, frames);
    for (int it = 0; it < NITER; ++it) {
        k_ola<<<(BB * LPAD) / 256, 256, 0, stream>>>(frames, wsq, xp);
        k_fused<<<BB * TT, 256, 0, stream>>>(xp, frames, mag, tprv,
                                             tw1024, tw2048, win);
    }
    k_ola_out<<<(BB * LL) / 256, 256, 0, stream>>>(frames, wsq, (float*)d_out);
}